// Round 4
// baseline (1434.293 us; speedup 1.0000x reference)
//
#include <hip/hip_runtime.h>
#include <hip/hip_bf16.h>
#include <stdint.h>

// Problem: x (8,4096,512) f32 -> NQ=32768 rows; codebook (4096,512) f32.
// Outputs f32 concat: q_st[NQ*D], commitment[NQ], cbn[M*D]
#define NQ 32768
#define D  512
#define M  4096
#define TAU 1e-5f

typedef __bf16 bf16x8 __attribute__((ext_vector_type(8)));
typedef float  f32x4  __attribute__((ext_vector_type(4)));

// ---------------- helpers ----------------
__device__ __forceinline__ unsigned short f2bf(float f) {
    unsigned u = __float_as_uint(f);
    u += 0x7fff + ((u >> 16) & 1);          // RNE
    return (unsigned short)(u >> 16);
}
__device__ __forceinline__ float bf2f(unsigned short h) {
    return __uint_as_float(((unsigned)h) << 16);
}
__device__ __forceinline__ void gl2lds16(const void* g, void* l) {
    __builtin_amdgcn_global_load_lds(
        (const __attribute__((address_space(1))) unsigned int*)g,
        (__attribute__((address_space(3))) unsigned int*)l,
        16, 0, 0);
}

// ---------------- Kernel: normalize codebook rows -> cbn (f32 output) -----
__global__ void k_norm_cb(const float* __restrict__ cb, float* __restrict__ cbn) {
    int row = blockIdx.x;
    const float2* src = (const float2*)(cb + (size_t)row * D);
    float2 v = src[threadIdx.x];
    float ss = v.x * v.x + v.y * v.y;
    #pragma unroll
    for (int o = 32; o > 0; o >>= 1) ss += __shfl_down(ss, o, 64);
    __shared__ float partial[4];
    __shared__ float scale_s;
    if ((threadIdx.x & 63) == 0) partial[threadIdx.x >> 6] = ss;
    __syncthreads();
    if (threadIdx.x == 0) {
        float t = partial[0] + partial[1] + partial[2] + partial[3];
        scale_s = 1.0f / fmaxf(sqrtf(t), 1e-12f);
    }
    __syncthreads();
    float sc = scale_s;
    float2 o2; o2.x = v.x * sc; o2.y = v.y * sc;
    ((float2*)(cbn + (size_t)row * D))[threadIdx.x] = o2;
}

// ---------------- Kernel: retile cbn -> A-fragment chunk layout -----------
// chunk idx = t16*1024 + kstep*64 + lane  (16B units), lane = quad*16+l15
// chunk holds cbn[t16*16 + l15][kstep*32 + quad*8 .. +8] as bf16 hi/lo
__global__ void k_tile_cb2(const float* __restrict__ cbn,
                           unsigned short* __restrict__ chi,
                           unsigned short* __restrict__ clo) {
    int p = blockIdx.x;                     // 256 blocks, 16 codes each
    __shared__ float xs[16][516];
    int t = threadIdx.x;
    #pragma unroll
    for (int i = 0; i < 8; i++) {
        int f = i * 256 + t;                // float4 id 0..2047
        int row = f >> 7, c4 = f & 127;
        float4 v = *(const float4*)(cbn + ((size_t)p * 16 + row) * D + c4 * 4);
        xs[row][c4 * 4 + 0] = v.x; xs[row][c4 * 4 + 1] = v.y;
        xs[row][c4 * 4 + 2] = v.z; xs[row][c4 * 4 + 3] = v.w;
    }
    __syncthreads();
    #pragma unroll
    for (int i = 0; i < 4; i++) {
        int c = i * 256 + t;                // chunk 0..1023
        int kstep = c >> 6, quad = (c >> 4) & 3, l15 = c & 15;
        int k0 = kstep * 32 + quad * 8;
        unsigned short h[8], l[8];
        #pragma unroll
        for (int j = 0; j < 8; j++) {
            float v = xs[l15][k0 + j];
            h[j] = f2bf(v);
            l[j] = f2bf(v - bf2f(h[j]));
        }
        int4 hv, lv;
        hv.x = h[0] | (h[1] << 16); hv.y = h[2] | (h[3] << 16);
        hv.z = h[4] | (h[5] << 16); hv.w = h[6] | (h[7] << 16);
        lv.x = l[0] | (l[1] << 16); lv.y = l[2] | (l[3] << 16);
        lv.z = l[4] | (l[5] << 16); lv.w = l[6] | (l[7] << 16);
        *(int4*)(chi + ((size_t)p * 1024 + c) * 8) = hv;
        *(int4*)(clo + ((size_t)p * 1024 + c) * 8) = lv;
    }
}

// ---------------- Kernel: x norms + normalized bf16 hi/lo in frag layout --
// 16 rows per block; chunk idx = p*1024 + kstep*64 + quad*16 + l15
__global__ void k_prep_x2(const float* __restrict__ x, float* __restrict__ invn,
                          unsigned short* __restrict__ xh, unsigned short* __restrict__ xl) {
    int p = blockIdx.x;                     // 2048 blocks
    __shared__ float xs[16][516];
    __shared__ float part[16][17];
    __shared__ float ivs[16];
    int t = threadIdx.x;
    #pragma unroll
    for (int i = 0; i < 8; i++) {
        int f = i * 256 + t;
        int row = f >> 7, c4 = f & 127;
        float4 v = *(const float4*)(x + ((size_t)p * 16 + row) * D + c4 * 4);
        xs[row][c4 * 4 + 0] = v.x; xs[row][c4 * 4 + 1] = v.y;
        xs[row][c4 * 4 + 2] = v.z; xs[row][c4 * 4 + 3] = v.w;
    }
    __syncthreads();
    {
        int row = t & 15, seg = t >> 4;
        float s = 0.f;
        #pragma unroll
        for (int j = 0; j < 32; j++) { float v = xs[row][seg * 32 + j]; s += v * v; }
        part[seg][row] = s;
    }
    __syncthreads();
    if (t < 16) {
        float ss = 0.f;
        #pragma unroll
        for (int s8 = 0; s8 < 16; s8++) ss += part[s8][t];
        float iv = 1.0f / fmaxf(sqrtf(ss), 1e-12f);
        ivs[t] = iv;
        invn[(size_t)p * 16 + t] = iv;
    }
    __syncthreads();
    #pragma unroll
    for (int i = 0; i < 4; i++) {
        int c = i * 256 + t;
        int kstep = c >> 6, quad = (c >> 4) & 3, l15 = c & 15;
        int k0 = kstep * 32 + quad * 8;
        float iv = ivs[l15];
        unsigned short h[8], l[8];
        #pragma unroll
        for (int j = 0; j < 8; j++) {
            float v = xs[l15][k0 + j] * iv;
            h[j] = f2bf(v);
            l[j] = f2bf(v - bf2f(h[j]));
        }
        int4 hv, lv;
        hv.x = h[0] | (h[1] << 16); hv.y = h[2] | (h[3] << 16);
        hv.z = h[4] | (h[5] << 16); hv.w = h[6] | (h[7] << 16);
        lv.x = l[0] | (l[1] << 16); lv.y = l[2] | (l[3] << 16);
        lv.z = l[4] | (l[5] << 16); lv.w = l[6] | (l[7] << 16);
        *(int4*)(xh + ((size_t)p * 1024 + c) * 8) = hv;
        *(int4*)(xl + ((size_t)p * 1024 + c) * 8) = lv;
    }
}

// ---------------- Kernel: barrier-free MFMA screen ------------------------
// 512 blocks x 512 threads. Block owns 64 queries (x hi/lo resident in LDS);
// wave w streams codebook tiles [w*32, w*32+32) from global into registers.
// No __syncthreads in the K-loop.
__launch_bounds__(512, 2)
__global__ void k_screen2(const unsigned short* __restrict__ xh_g,
                          const unsigned short* __restrict__ xl_g,
                          const unsigned short* __restrict__ chi,
                          const unsigned short* __restrict__ clo,
                          float* __restrict__ bestv, float* __restrict__ marg,
                          int* __restrict__ i1g, int* __restrict__ i2g) {
    __shared__ bf16x8 XH[4096];             // 64 KB: chunk = (qf*16+ks)*64 + lane
    __shared__ bf16x8 XL[4096];             // 64 KB
    __shared__ float mv[8][64], ms[8][64];
    __shared__ int   mi[8][64], mi2[8][64];

    int tid = threadIdx.x;
    int lane = tid & 63, w = tid >> 6;
    int l15 = lane & 15, quad = lane >> 4;

    // one-time stage of x fragments (gl2lds: wave-uniform base + lane*16)
    {
        const char* gh  = (const char*)xh_g + (size_t)blockIdx.x * 65536;
        const char* gl_ = (const char*)xl_g + (size_t)blockIdx.x * 65536;
        #pragma unroll
        for (int i = 0; i < 8; i++) {
            int s = w * 8 + i;              // chunk-group 0..63 (wave-uniform)
            gl2lds16(gh  + (size_t)s * 1024 + lane * 16, (void*)(XH + s * 64));
            gl2lds16(gl_ + (size_t)s * 1024 + lane * 16, (void*)(XL + s * 64));
        }
    }
    __syncthreads();                        // the ONLY pre-epilogue barrier

    float best[4], second[4]; int bi[4], bi2[4];
    #pragma unroll
    for (int qf = 0; qf < 4; qf++) { best[qf] = -1e30f; second[qf] = -1e30f; bi[qf] = 0; bi2[qf] = 0; }

    const char* Ah = (const char*)chi;
    const char* Al = (const char*)clo;

    for (int g = 0; g < 8; g++) {
        int t0 = w * 32 + g * 4;            // my 4 code-tiles this group
        f32x4 acc[4][4];
        #pragma unroll
        for (int ct = 0; ct < 4; ct++)
            #pragma unroll
            for (int qf = 0; qf < 4; qf++) acc[ct][qf] = (f32x4){0.f, 0.f, 0.f, 0.f};

        #pragma unroll
        for (int ks = 0; ks < 16; ks++) {
            bf16x8 ah[4], al[4];
            #pragma unroll
            for (int ct = 0; ct < 4; ct++) {
                int off = ((t0 + ct) * 16 + ks) * 1024 + lane * 16;
                ah[ct] = *(const bf16x8*)(Ah + off);
                al[ct] = *(const bf16x8*)(Al + off);
            }
            bf16x8 bh[4], bl[4];
            #pragma unroll
            for (int qf = 0; qf < 4; qf++) {
                bh[qf] = XH[(qf * 16 + ks) * 64 + lane];
                bl[qf] = XL[(qf * 16 + ks) * 64 + lane];
            }
            #pragma unroll
            for (int ct = 0; ct < 4; ct++) {
                #pragma unroll
                for (int qf = 0; qf < 4; qf++) {
                    acc[ct][qf] = __builtin_amdgcn_mfma_f32_16x16x32_bf16(ah[ct], bh[qf], acc[ct][qf], 0, 0, 0);
                    acc[ct][qf] = __builtin_amdgcn_mfma_f32_16x16x32_bf16(ah[ct], bl[qf], acc[ct][qf], 0, 0, 0);
                    acc[ct][qf] = __builtin_amdgcn_mfma_f32_16x16x32_bf16(al[ct], bh[qf], acc[ct][qf], 0, 0, 0);
                }
            }
        }
        // epilogue: per-lane top-2 per query-frag; indices ascend (g, ct, r)
        #pragma unroll
        for (int qf = 0; qf < 4; qf++) {
            #pragma unroll
            for (int ct = 0; ct < 4; ct++) {
                #pragma unroll
                for (int r = 0; r < 4; r++) {
                    float v = acc[ct][qf][r];
                    int ci = (t0 + ct) * 16 + quad * 4 + r;
                    bool b1 = v > best[qf];
                    bool b2 = v > second[qf];
                    float ns = b1 ? best[qf] : (b2 ? v : second[qf]);
                    int  ni2 = b1 ? bi[qf]   : (b2 ? ci : bi2[qf]);
                    best[qf] = b1 ? v : best[qf];
                    bi[qf]   = b1 ? ci : bi[qf];
                    second[qf] = ns;
                    bi2[qf]    = ni2;
                }
            }
        }
    }

    // quad merge (lanes with same l15 hold same queries, different codes)
    #pragma unroll
    for (int qf = 0; qf < 4; qf++) {
        #pragma unroll
        for (int mm = 16; mm <= 32; mm <<= 1) {
            float ob  = __shfl_xor(best[qf], mm, 64);
            float os  = __shfl_xor(second[qf], mm, 64);
            int   oi  = __shfl_xor(bi[qf], mm, 64);
            int   oi2 = __shfl_xor(bi2[qf], mm, 64);
            bool take = (ob > best[qf]) || (ob == best[qf] && oi < bi[qf]);
            float wv = take ? ob : best[qf];      int wi  = take ? oi : bi[qf];
            float c1 = take ? best[qf] : ob;      int c1i = take ? bi[qf] : oi;
            float c2 = take ? os : second[qf];    int c2i = take ? oi2 : bi2[qf];
            bool t2 = (c2 > c1) || (c2 == c1 && c2i < c1i);
            best[qf] = wv; bi[qf] = wi;
            second[qf] = t2 ? c2 : c1;
            bi2[qf]    = t2 ? c2i : c1i;
        }
    }
    if (quad == 0) {
        #pragma unroll
        for (int qf = 0; qf < 4; qf++) {
            mv[w][qf * 16 + l15]  = best[qf];
            ms[w][qf * 16 + l15]  = second[qf];
            mi[w][qf * 16 + l15]  = bi[qf];
            mi2[w][qf * 16 + l15] = bi2[qf];
        }
    }
    __syncthreads();
    // cross-wave merge: thread qq (<64) merges 8 wave-results for its query
    if (tid < 64) {
        float b1 = mv[0][tid], s1 = ms[0][tid];
        int   j1 = mi[0][tid], j2 = mi2[0][tid];
        for (int ww = 1; ww < 8; ww++) {
            float ob = mv[ww][tid], os = ms[ww][tid];
            int   oi = mi[ww][tid], oi2 = mi2[ww][tid];
            bool take = (ob > b1) || (ob == b1 && oi < j1);
            float wv = take ? ob : b1;   int wi  = take ? oi : j1;
            float c1 = take ? b1 : ob;   int c1i = take ? j1 : oi;
            float c2 = take ? os : s1;   int c2i = take ? oi2 : j2;
            bool t2 = (c2 > c1) || (c2 == c1 && c2i < c1i);
            b1 = wv; j1 = wi;
            s1 = t2 ? c2 : c1;
            j2 = t2 ? c2i : c1i;
        }
        int q = blockIdx.x * 64 + tid;
        bestv[q] = b1;
        marg[q]  = b1 - s1;
        i1g[q]   = j1;
        i2g[q]   = j2;
    }
}

// ---------------- Kernel: gather + commitment, with top-2 exact fixup -----
__global__ void k_write_fix(const float* __restrict__ x, const float* __restrict__ invn,
                            const float* __restrict__ cbn, const float* __restrict__ marg,
                            const float* __restrict__ bestv,
                            const int* __restrict__ idx1, const int* __restrict__ idx2,
                            float* __restrict__ outq, float* __restrict__ outc) {
    int wave = threadIdx.x >> 6, lane = threadIdx.x & 63;
    int row = blockIdx.x * 4 + wave;

    float mdot;
    int id;
    if (marg[row] < TAU) {
        int i1 = idx1[row], i2 = idx2[row];
        float iv = invn[row];
        const float4* xr = (const float4*)(x + (size_t)row * D);
        const float4* c1 = (const float4*)(cbn + (size_t)i1 * D);
        const float4* c2 = (const float4*)(cbn + (size_t)i2 * D);
        float4 xa = xr[lane], xb = xr[lane + 64];
        float4 p = c1[lane], q4 = c1[lane + 64];
        float d1 = xa.x*p.x + xa.y*p.y + xa.z*p.z + xa.w*p.w
                 + xb.x*q4.x + xb.y*q4.y + xb.z*q4.z + xb.w*q4.w;
        p = c2[lane]; q4 = c2[lane + 64];
        float d2 = xa.x*p.x + xa.y*p.y + xa.z*p.z + xa.w*p.w
                 + xb.x*q4.x + xb.y*q4.y + xb.z*q4.z + xb.w*q4.w;
        #pragma unroll
        for (int o = 32; o > 0; o >>= 1) {
            d1 += __shfl_xor(d1, o, 64);
            d2 += __shfl_xor(d2, o, 64);
        }
        bool take2 = (d2 > d1) || (d2 == d1 && i2 < i1);
        id   = take2 ? i2 : i1;
        mdot = (take2 ? d2 : d1) * iv;
    } else {
        id   = idx1[row];
        mdot = bestv[row];
    }

    const float4* src = (const float4*)(cbn + (size_t)id * D);
    float4* dst = (float4*)(outq + (size_t)row * D);
    dst[lane]      = src[lane];
    dst[lane + 64] = src[lane + 64];
    if (lane == 0) outc[row] = 1.0f - mdot;
}

// ================= fallback path (round-1 f32 VALU) ======================
__global__ void k_xnorm(const float* __restrict__ x, float* __restrict__ invn) {
    int wave = threadIdx.x >> 6, lane = threadIdx.x & 63;
    int row = blockIdx.x * 4 + wave;
    const float4* src = (const float4*)(x + (size_t)row * D);
    float4 a = src[lane];
    float4 b = src[lane + 64];
    float ss = a.x*a.x + a.y*a.y + a.z*a.z + a.w*a.w
             + b.x*b.x + b.y*b.y + b.z*b.z + b.w*b.w;
    #pragma unroll
    for (int o = 32; o > 0; o >>= 1) ss += __shfl_down(ss, o, 64);
    if (lane == 0) invn[row] = 1.0f / fmaxf(sqrtf(ss), 1e-12f);
}

#define BN 64
#define BM 64
#define BK 16
#define LSTR 68

__launch_bounds__(256, 2)
__global__ void k_argmax(const float* __restrict__ x, const float* __restrict__ cbn,
                         float* __restrict__ maxdot, int* __restrict__ idxout) {
    __shared__ __align__(16) float xs[BK * LSTR];
    __shared__ __align__(16) float cs[BK * LSTR];
    int tid = threadIdx.x;
    int tx = tid & 15, ty = tid >> 4;
    int qbase = blockIdx.x * BN;
    int sq = tid >> 2;
    int skseg = (tid & 3) * 4;
    const float* xg  = x   + ((size_t)(qbase + sq)) * D + skseg;
    const float* cg0 = cbn + ((size_t)sq) * D + skseg;
    float best[4]; int bidx[4];
    #pragma unroll
    for (int i = 0; i < 4; i++) { best[i] = -1e30f; bidx[i] = 0; }
    for (int mt = 0; mt < M / BM; mt++) {
        float s[4][4] = {};
        const float* cg = cg0 + (size_t)mt * BM * D;
        float4 ax = *(const float4*)(xg);
        float4 ac = *(const float4*)(cg);
        for (int kt = 0; kt < D / BK; kt++) {
            __syncthreads();
            xs[(skseg + 0) * LSTR + sq] = ax.x;
            xs[(skseg + 1) * LSTR + sq] = ax.y;
            xs[(skseg + 2) * LSTR + sq] = ax.z;
            xs[(skseg + 3) * LSTR + sq] = ax.w;
            cs[(skseg + 0) * LSTR + sq] = ac.x;
            cs[(skseg + 1) * LSTR + sq] = ac.y;
            cs[(skseg + 2) * LSTR + sq] = ac.z;
            cs[(skseg + 3) * LSTR + sq] = ac.w;
            if (kt + 1 < D / BK) {
                ax = *(const float4*)(xg + (kt + 1) * BK);
                ac = *(const float4*)(cg + (kt + 1) * BK);
            }
            __syncthreads();
            #pragma unroll
            for (int k = 0; k < BK; k++) {
                float4 a = *(const float4*)&xs[k * LSTR + ty * 4];
                float4 b = *(const float4*)&cs[k * LSTR + tx * 4];
                s[0][0] = fmaf(a.x, b.x, s[0][0]); s[0][1] = fmaf(a.x, b.y, s[0][1]);
                s[0][2] = fmaf(a.x, b.z, s[0][2]); s[0][3] = fmaf(a.x, b.w, s[0][3]);
                s[1][0] = fmaf(a.y, b.x, s[1][0]); s[1][1] = fmaf(a.y, b.y, s[1][1]);
                s[1][2] = fmaf(a.y, b.z, s[1][2]); s[1][3] = fmaf(a.y, b.w, s[1][3]);
                s[2][0] = fmaf(a.z, b.x, s[2][0]); s[2][1] = fmaf(a.z, b.y, s[2][1]);
                s[2][2] = fmaf(a.z, b.z, s[2][2]); s[2][3] = fmaf(a.z, b.w, s[2][3]);
                s[3][0] = fmaf(a.w, b.x, s[3][0]); s[3][1] = fmaf(a.w, b.y, s[3][1]);
                s[3][2] = fmaf(a.w, b.z, s[3][2]); s[3][3] = fmaf(a.w, b.w, s[3][3]);
            }
        }
        #pragma unroll
        for (int i = 0; i < 4; i++) {
            #pragma unroll
            for (int j = 0; j < 4; j++) {
                int ci = mt * BM + tx * 4 + j;
                if (s[i][j] > best[i]) { best[i] = s[i][j]; bidx[i] = ci; }
            }
        }
    }
    __syncthreads();
    float* rv = xs;
    int*   ri = (int*)cs;
    #pragma unroll
    for (int i = 0; i < 4; i++) {
        rv[(ty * 4 + i) * 16 + tx] = best[i];
        ri[(ty * 4 + i) * 16 + tx] = bidx[i];
    }
    __syncthreads();
    if (tid < BN) {
        float bv = rv[tid * 16]; int bb = ri[tid * 16];
        for (int t = 1; t < 16; t++) {
            float v = rv[tid * 16 + t]; int id = ri[tid * 16 + t];
            if (v > bv || (v == bv && id < bb)) { bv = v; bb = id; }
        }
        maxdot[qbase + tid] = bv;
        idxout[qbase + tid] = bb;
    }
}

__global__ void k_write_old(const float* __restrict__ cbn, const int* __restrict__ idx,
                            const float* __restrict__ maxdot, const float* __restrict__ invn,
                            float* __restrict__ outq, float* __restrict__ outc) {
    int wave = threadIdx.x >> 6, lane = threadIdx.x & 63;
    int row = blockIdx.x * 4 + wave;
    int id = idx[row];
    const float4* src = (const float4*)(cbn + (size_t)id * D);
    float4* dst = (float4*)(outq + (size_t)row * D);
    dst[lane]      = src[lane];
    dst[lane + 64] = src[lane + 64];
    if (lane == 0) outc[row] = 1.0f - maxdot[row] * invn[row];
}

// ================= launch =================================================
extern "C" void kernel_launch(void* const* d_in, const int* in_sizes, int n_in,
                              void* d_out, int out_size, void* d_ws, size_t ws_size,
                              hipStream_t stream) {
    const float* x  = (const float*)d_in[0];
    const float* cb = (const float*)d_in[1];
    float* out  = (float*)d_out;
    float* outq = out;
    float* outc = out + (size_t)NQ * D;
    float* cbn  = outc + NQ;

    float* invn   = (float*)d_ws;
    float* maxdot = invn + NQ;
    float* marg   = maxdot + NQ;
    int*   idx    = (int*)(marg + NQ);
    int*   idx2   = idx + NQ;
    unsigned short* xh    = (unsigned short*)(idx2 + NQ);
    unsigned short* xl    = xh + (size_t)NQ * D;
    unsigned short* chi_t = xl + (size_t)NQ * D;
    unsigned short* clo_t = chi_t + (size_t)M * D;
    size_t needed = (size_t)((char*)(clo_t + (size_t)M * D) - (char*)d_ws);

    k_norm_cb<<<M, 256, 0, stream>>>(cb, cbn);

    if (ws_size >= needed) {
        k_prep_x2<<<NQ / 16, 256, 0, stream>>>(x, invn, xh, xl);
        k_tile_cb2<<<M / 16, 256, 0, stream>>>(cbn, chi_t, clo_t);
        k_screen2<<<NQ / 64, 512, 0, stream>>>(xh, xl, chi_t, clo_t, maxdot, marg, idx, idx2);
        k_write_fix<<<NQ / 4, 256, 0, stream>>>(x, invn, cbn, marg, maxdot, idx, idx2, outq, outc);
    } else {
        k_xnorm<<<NQ / 4, 256, 0, stream>>>(x, invn);
        k_argmax<<<NQ / BN, 256, 0, stream>>>(x, cbn, maxdot, idx);
        k_write_old<<<NQ / 4, 256, 0, stream>>>(cbn, idx, maxdot, invn, outq, outc);
    }
}